// Round 1
// baseline (79.048 us; speedup 1.0000x reference)
//
#include <hip/hip_runtime.h>
#include <stdint.h>
#include <stddef.h>

#define BB 4
#define MM 512
#define NN 512
#define EE 256
#define HH 16
#define DD 16

typedef __bf16 bf16x8 __attribute__((ext_vector_type(8)));
typedef float f32x4 __attribute__((ext_vector_type(4)));

static __device__ __forceinline__ bf16x8 bzero8() {
  bf16x8 z;
#pragma unroll
  for (int i = 0; i < 8; ++i) z[i] = (__bf16)0.0f;
  return z;
}

static __device__ __forceinline__ bf16x8 cvt8(const float* __restrict__ p) {
  const float4 u = *(const float4*)p;
  const float4 v = *(const float4*)(p + 4);
  bf16x8 r;
  r[0] = (__bf16)u.x; r[1] = (__bf16)u.y; r[2] = (__bf16)u.z; r[3] = (__bf16)u.w;
  r[4] = (__bf16)v.x; r[5] = (__bf16)v.y; r[6] = (__bf16)v.z; r[7] = (__bf16)v.w;
  return r;
}

static __device__ __forceinline__ unsigned short f2b(float f) {
  union { __bf16 h; unsigned short u; } cv;
  cv.h = (__bf16)f;
  return cv.u;
}

// ---------------------------------------------------------------------------
// Q projection: Qs[b][h][m][d] = bf16( 0.25 * (q_input @ Wq^T) )   (0.25 = 1/sqrt(D))
// grid (64 token-tiles of 32, 4 col-tiles of 64), 256 threads (4 waves)
// ---------------------------------------------------------------------------
__global__ __launch_bounds__(256) void proj_q_kernel(
    const float* __restrict__ X, const float* __restrict__ Wq,
    unsigned short* __restrict__ Qs) {
  const int tid = threadIdx.x, w = tid >> 6, l = tid & 63;
  const int lg = l >> 4, lr = l & 15;
  const int t0 = blockIdx.x * 32 + (w & 1) * 16;
  const int n0 = blockIdx.y * 64 + (w >> 1) * 32;
  f32x4 acc0 = {0.f, 0.f, 0.f, 0.f}, acc1 = {0.f, 0.f, 0.f, 0.f};
#pragma unroll
  for (int kc = 0; kc < EE; kc += 32) {
    const int k = kc + lg * 8;
    bf16x8 a  = cvt8(X  + (size_t)(t0 + lr) * EE + k);
    bf16x8 b0 = cvt8(Wq + (size_t)(n0 + lr) * EE + k);
    bf16x8 b1 = cvt8(Wq + (size_t)(n0 + 16 + lr) * EE + k);
    acc0 = __builtin_amdgcn_mfma_f32_16x16x32_bf16(a, b0, acc0, 0, 0, 0);
    acc1 = __builtin_amdgcn_mfma_f32_16x16x32_bf16(a, b1, acc1, 0, 0, 0);
  }
#pragma unroll
  for (int r = 0; r < 4; ++r) {
    const int t = t0 + 4 * lg + r, b = t >> 9, m = t & 511;
    const int j0 = n0 + lr, j1 = j0 + 16;
    Qs[((size_t)(b * HH + (j0 >> 4)) * MM + m) * DD + (j0 & 15)] = f2b(acc0[r] * 0.25f);
    Qs[((size_t)(b * HH + (j1 >> 4)) * MM + m) * DD + (j1 & 15)] = f2b(acc1[r] * 0.25f);
  }
}

// ---------------------------------------------------------------------------
// KV projection: rows j<256 -> Ks[b][h][n][d] ; j>=256 -> Vt[b][h][d][n] (transposed)
// grid (64, 8), 256 threads
// ---------------------------------------------------------------------------
__global__ __launch_bounds__(256) void proj_kv_kernel(
    const float* __restrict__ X, const float* __restrict__ Wkv,
    unsigned short* __restrict__ Ks, unsigned short* __restrict__ Vt) {
  const int tid = threadIdx.x, w = tid >> 6, l = tid & 63;
  const int lg = l >> 4, lr = l & 15;
  const int t0 = blockIdx.x * 32 + (w & 1) * 16;
  const int n0 = blockIdx.y * 64 + (w >> 1) * 32;
  f32x4 acc0 = {0.f, 0.f, 0.f, 0.f}, acc1 = {0.f, 0.f, 0.f, 0.f};
#pragma unroll
  for (int kc = 0; kc < EE; kc += 32) {
    const int k = kc + lg * 8;
    bf16x8 a  = cvt8(X   + (size_t)(t0 + lr) * EE + k);
    bf16x8 b0 = cvt8(Wkv + (size_t)(n0 + lr) * EE + k);
    bf16x8 b1 = cvt8(Wkv + (size_t)(n0 + 16 + lr) * EE + k);
    acc0 = __builtin_amdgcn_mfma_f32_16x16x32_bf16(a, b0, acc0, 0, 0, 0);
    acc1 = __builtin_amdgcn_mfma_f32_16x16x32_bf16(a, b1, acc1, 0, 0, 0);
  }
#pragma unroll
  for (int r = 0; r < 4; ++r) {
    const int t = t0 + 4 * lg + r, b = t >> 9, n = t & 511;
#pragma unroll
    for (int fi = 0; fi < 2; ++fi) {
      const int j = n0 + lr + fi * 16;
      const float v = fi ? acc1[r] : acc0[r];
      if (j < 256) {
        Ks[((size_t)(b * HH + (j >> 4)) * NN + n) * DD + (j & 15)] = f2b(v);
      } else {
        const int jj = j - 256;
        Vt[((size_t)(b * HH + (jj >> 4)) * DD + (jj & 15)) * NN + n] = f2b(v);
      }
    }
  }
}

// ---------------------------------------------------------------------------
// Fused attention: scores(MFMA) -> MLP mix (VALU, on C-fragments) -> softmax
// -> PV (MFMA). One block = (b, h, 32-row m-tile); 4 waves, each owns 128 n.
// ---------------------------------------------------------------------------
__global__ __launch_bounds__(256) void attn_kernel(
    const unsigned short* __restrict__ Qs, const unsigned short* __restrict__ Ks,
    const unsigned short* __restrict__ Vt, const float* __restrict__ dmat,
    const float* __restrict__ W1, const float* __restrict__ b1v,
    const float* __restrict__ W2, float* __restrict__ attn) {
  __shared__ unsigned short P[32][520];       // exp'd probs, bf16, padded row
  __shared__ float red[4][32];                // per-wave row partials
  __shared__ float rowv[32];                  // final rowmax, then rowsum
  __shared__ float pvred[4][2][16][16];       // PV partials per wave

  const int tid = threadIdx.x, w = tid >> 6, l = tid & 63;
  const int lg = l >> 4, lr = l & 15;
  const int bid = blockIdx.x;
  const int mt = bid & 15, h = (bid >> 4) & 15, b = bid >> 8;
  const int m0 = mt * 32;
  const int n0 = w * 128;

  const unsigned short* Qbase = Qs + ((size_t)(b * HH + h) * MM + m0) * DD;
  const unsigned short* Kbase = Ks + (size_t)(b * HH + h) * NN * DD;
  const unsigned short* Vbase = Vt + (size_t)(b * HH + h) * DD * NN;
  const float* dbase = dmat + (size_t)b * MM * NN;

  // Q A-fragments, zero-padded in K upper half (D=16 < K=32)
  bf16x8 qa[2];
#pragma unroll
  for (int mb = 0; mb < 2; ++mb) {
    qa[mb] = bzero8();
    if (lg < 2) qa[mb] = *(const bf16x8*)(Qbase + (mb * 16 + lr) * DD + lg * 8);
  }

  f32x4 zf = {0.f, 0.f, 0.f, 0.f};
  f32x4 c[2][8];
#pragma unroll
  for (int mb = 0; mb < 2; ++mb)
#pragma unroll
    for (int nb = 0; nb < 8; ++nb) c[mb][nb] = zf;

#pragma unroll
  for (int nb = 0; nb < 8; ++nb) {
    bf16x8 kb = bzero8();
    if (lg < 2)
      kb = *(const bf16x8*)(Kbase + (size_t)(n0 + nb * 16 + lr) * DD + lg * 8);
    c[0][nb] = __builtin_amdgcn_mfma_f32_16x16x32_bf16(qa[0], kb, c[0][nb], 0, 0, 0);
    c[1][nb] = __builtin_amdgcn_mfma_f32_16x16x32_bf16(qa[1], kb, c[1][nb], 0, 0, 0);
  }

  // MLP coefficients (uniform per block -> scalar regs).
  // relu(x) = (x+|x|)/2:  mixed = Ac*s + Cc*d + sum_k wk*|a_k s + c_k d + b_k|
  // (+ per-row constant, dropped: softmax shift-invariant)
  float ak[16], ck[16], bk[16], wk[16];
  float Ac = 0.f, Cc = 0.f;
#pragma unroll
  for (int k = 0; k < 16; ++k) {
    ak[k] = W1[h * 32 + k];
    ck[k] = W1[h * 32 + 16 + k];
    bk[k] = b1v[h * 16 + k];
    wk[k] = 0.5f * W2[h * 16 + k];
    Ac += wk[k] * ak[k];
    Cc += wk[k] * ck[k];
  }

  float pmax[2][4];
#pragma unroll
  for (int mb = 0; mb < 2; ++mb)
#pragma unroll
    for (int r = 0; r < 4; ++r) pmax[mb][r] = -3.4e38f;

#pragma unroll
  for (int mb = 0; mb < 2; ++mb) {
    const int mrow = m0 + mb * 16 + 4 * lg;
#pragma unroll
    for (int nb = 0; nb < 8; ++nb) {
      const int ncol = n0 + nb * 16 + lr;
      const float* dp = dbase + (size_t)mrow * NN + ncol;
      float dv[4];
#pragma unroll
      for (int r = 0; r < 4; ++r) dv[r] = dp[(size_t)r * NN];
#pragma unroll
      for (int r = 0; r < 4; ++r) {
        const float s = c[mb][nb][r];
        const float d = dv[r];
        float acc = fmaf(Ac, s, Cc * d);
#pragma unroll
        for (int k = 0; k < 16; ++k) {
          const float t = fmaf(ak[k], s, fmaf(ck[k], d, bk[k]));
          acc = fmaf(wk[k], fabsf(t), acc);
        }
        c[mb][nb][r] = acc;
        pmax[mb][r] = fmaxf(pmax[mb][r], acc);
      }
    }
  }

  // row max: shfl within 16-lane group, then cross-wave via LDS
#pragma unroll
  for (int mb = 0; mb < 2; ++mb)
#pragma unroll
    for (int r = 0; r < 4; ++r) {
#pragma unroll
      for (int off = 8; off > 0; off >>= 1)
        pmax[mb][r] = fmaxf(pmax[mb][r], __shfl_xor(pmax[mb][r], off, 16));
      if (lr == 0) red[w][mb * 16 + 4 * lg + r] = pmax[mb][r];
    }
  __syncthreads();
  if (tid < 32)
    rowv[tid] = fmaxf(fmaxf(red[0][tid], red[1][tid]), fmaxf(red[2][tid], red[3][tid]));
  __syncthreads();

  float rm[2][4];
#pragma unroll
  for (int mb = 0; mb < 2; ++mb)
#pragma unroll
    for (int r = 0; r < 4; ++r) rm[mb][r] = rowv[mb * 16 + 4 * lg + r];

  // exp, partial row-sums, write P (bf16) for the C->A fragment transpose
  float psum[2][4] = {};
#pragma unroll
  for (int mb = 0; mb < 2; ++mb)
#pragma unroll
    for (int nb = 0; nb < 8; ++nb)
#pragma unroll
      for (int r = 0; r < 4; ++r) {
        const float e = __expf(c[mb][nb][r] - rm[mb][r]);
        psum[mb][r] += e;
        P[mb * 16 + 4 * lg + r][n0 + nb * 16 + lr] = f2b(e);
      }
#pragma unroll
  for (int mb = 0; mb < 2; ++mb)
#pragma unroll
    for (int r = 0; r < 4; ++r) {
#pragma unroll
      for (int off = 8; off > 0; off >>= 1)
        psum[mb][r] += __shfl_xor(psum[mb][r], off, 16);
      if (lr == 0) red[w][mb * 16 + 4 * lg + r] = psum[mb][r];
    }

  // PV: each wave contracts over its own n-range (P rows it wrote itself;
  // intra-wave LDS dependency -> compiler-inserted lgkmcnt, no barrier needed)
  f32x4 pv[2];
  pv[0] = zf; pv[1] = zf;
#pragma unroll
  for (int kb = 0; kb < 4; ++kb) {
    const bf16x8 vb = *(const bf16x8*)(Vbase + (size_t)lr * NN + (n0 + kb * 32 + lg * 8));
#pragma unroll
    for (int mb = 0; mb < 2; ++mb) {
      const bf16x8 pa = *(const bf16x8*)(&P[mb * 16 + lr][n0 + kb * 32 + lg * 8]);
      pv[mb] = __builtin_amdgcn_mfma_f32_16x16x32_bf16(pa, vb, pv[mb], 0, 0, 0);
    }
  }
#pragma unroll
  for (int mb = 0; mb < 2; ++mb)
#pragma unroll
    for (int r = 0; r < 4; ++r) pvred[w][mb][4 * lg + r][lr] = pv[mb][r];
  __syncthreads();
  if (tid < 32) rowv[tid] = red[0][tid] + red[1][tid] + red[2][tid] + red[3][tid];
  __syncthreads();

  for (int i = tid; i < 512; i += 256) {
    const int mr = i >> 4, dd = i & 15;
    const float s = pvred[0][mr >> 4][mr & 15][dd] + pvred[1][mr >> 4][mr & 15][dd] +
                    pvred[2][mr >> 4][mr & 15][dd] + pvred[3][mr >> 4][mr & 15][dd];
    attn[((size_t)(b * MM) + m0 + mr) * EE + h * DD + dd] = s / rowv[mr];
  }
}

// ---------------------------------------------------------------------------
// Final projection, fp32 VALU (precision headroom): out = attn @ Wout^T
// grid (32, 4), 256 threads, 64x64 tile, 4x4 micro-tile
// ---------------------------------------------------------------------------
__global__ __launch_bounds__(256) void out_gemm_kernel(
    const float* __restrict__ Aat, const float* __restrict__ Wout,
    float* __restrict__ out) {
  __shared__ float As[64][68];
  __shared__ float Bs[64][68];
  const int tid = threadIdx.x;
  const int m0 = blockIdx.x * 64, n0 = blockIdx.y * 64;
  const int tm = tid >> 4, tn = tid & 15;
  const int lrow = tid >> 2, lseg = (tid & 3) * 16;
  float acc[4][4] = {};
  for (int kc = 0; kc < 256; kc += 64) {
    __syncthreads();
#pragma unroll
    for (int i = 0; i < 4; ++i) {
      *(float4*)&As[lrow][lseg + i * 4] =
          *(const float4*)&Aat[(size_t)(m0 + lrow) * 256 + kc + lseg + i * 4];
      *(float4*)&Bs[lrow][lseg + i * 4] =
          *(const float4*)&Wout[(size_t)(n0 + lrow) * 256 + kc + lseg + i * 4];
    }
    __syncthreads();
#pragma unroll 4
    for (int k = 0; k < 64; ++k) {
      float a[4], bb[4];
#pragma unroll
      for (int i = 0; i < 4; ++i) a[i] = As[tm * 4 + i][k];
#pragma unroll
      for (int j = 0; j < 4; ++j) bb[j] = Bs[tn * 4 + j][k];
#pragma unroll
      for (int i = 0; i < 4; ++i)
#pragma unroll
        for (int j = 0; j < 4; ++j) acc[i][j] = fmaf(a[i], bb[j], acc[i][j]);
    }
  }
#pragma unroll
  for (int i = 0; i < 4; ++i)
#pragma unroll
    for (int j = 0; j < 4; ++j)
      out[(size_t)(m0 + tm * 4 + i) * 256 + n0 + tn * 4 + j] = acc[i][j];
}

// ---------------------------------------------------------------------------
extern "C" void kernel_launch(void* const* d_in, const int* in_sizes, int n_in,
                              void* d_out, int out_size, void* d_ws, size_t ws_size,
                              hipStream_t stream) {
  const float* q_input  = (const float*)d_in[0];
  const float* kv_input = (const float*)d_in[1];
  const float* dmat     = (const float*)d_in[2];
  const float* Wq       = (const float*)d_in[3];
  const float* Wkv      = (const float*)d_in[4];
  const float* W1       = (const float*)d_in[5];
  const float* b1       = (const float*)d_in[6];
  const float* W2       = (const float*)d_in[7];
  // d_in[8] = mix_b2: per-row constant inside softmax -> provably no effect, unused
  const float* Wout     = (const float*)d_in[9];
  float* out = (float*)d_out;

  char* ws = (char*)d_ws;
  unsigned short* Qs = (unsigned short*)(ws);                 // 1 MB  bf16 [B][H][M][D]
  unsigned short* Ks = (unsigned short*)(ws + (1u << 20));    // 1 MB  bf16 [B][H][N][D]
  unsigned short* Vt = (unsigned short*)(ws + (2u << 20));    // 1 MB  bf16 [B][H][D][N]
  float*          at = (float*)(ws + (3u << 20));             // 2 MB  f32  [B][M][E]

  proj_q_kernel<<<dim3(64, 4), 256, 0, stream>>>(q_input, Wq, Qs);
  proj_kv_kernel<<<dim3(64, 8), 256, 0, stream>>>(kv_input, Wkv, Ks, Vt);
  attn_kernel<<<dim3(1024), 256, 0, stream>>>(Qs, Ks, Vt, dmat, W1, b1, W2, at);
  out_gemm_kernel<<<dim3(32, 4), 256, 0, stream>>>(at, Wout, out);
}

// Round 2
// 63.781 us; speedup vs baseline: 1.2394x; 1.2394x over previous
//
#include <hip/hip_runtime.h>
#include <stdint.h>
#include <stddef.h>

#define MM 512
#define NN 512
#define EE 256
#define HH 16
#define DD 16

typedef __bf16 bf16x8 __attribute__((ext_vector_type(8)));
typedef float f32x4 __attribute__((ext_vector_type(4)));

static __device__ __forceinline__ bf16x8 bzero8() {
  bf16x8 z;
#pragma unroll
  for (int i = 0; i < 8; ++i) z[i] = (__bf16)0.0f;
  return z;
}

static __device__ __forceinline__ bf16x8 cvt8(const float* __restrict__ p) {
  const float4 u = *(const float4*)p;
  const float4 v = *(const float4*)(p + 4);
  bf16x8 r;
  r[0] = (__bf16)u.x; r[1] = (__bf16)u.y; r[2] = (__bf16)u.z; r[3] = (__bf16)u.w;
  r[4] = (__bf16)v.x; r[5] = (__bf16)v.y; r[6] = (__bf16)v.z; r[7] = (__bf16)v.w;
  return r;
}

static __device__ __forceinline__ unsigned short f2b(float f) {
  union { __bf16 h; unsigned short u; } cv;
  cv.h = (__bf16)f;
  return cv.u;
}

static __device__ __forceinline__ float b2f(unsigned short u) {
  union { unsigned int i; float f; } cv;
  cv.i = ((unsigned int)u) << 16;
  return cv.f;
}

// raw v_exp_f32: computes 2^x (we pre-scale by 1/ln2 in the MLP coefficients)
static __device__ __forceinline__ float fexp2(float x) {
  float r;
  asm("v_exp_f32 %0, %1" : "=v"(r) : "v"(x));
  return r;
}

static __device__ __forceinline__ float sload(const float* p) {
  return __int_as_float(__builtin_amdgcn_readfirstlane(__float_as_int(*p)));
}

// ---------------------------------------------------------------------------
// Fused projections. blockIdx.y: 0-3 -> Q proj, 4-11 -> KV proj, 12 -> Wout split
// ---------------------------------------------------------------------------
__global__ __launch_bounds__(256) void proj_all_kernel(
    const float* __restrict__ Xq, const float* __restrict__ Xkv,
    const float* __restrict__ Wq, const float* __restrict__ Wkv,
    const float* __restrict__ Wout,
    unsigned short* __restrict__ Qs, unsigned short* __restrict__ Ks,
    unsigned short* __restrict__ Vt,
    unsigned short* __restrict__ Whi, unsigned short* __restrict__ Wlo) {
  const int by = blockIdx.y;
  const int tid = threadIdx.x;

  if (by == 12) {
    // Wout -> bf16 hi/lo planes (65536 elements, 16384 threads x 4)
    const int base = (blockIdx.x * 256 + tid) * 4;
    const float4 v = *(const float4*)(Wout + base);
    float c[4] = {v.x, v.y, v.z, v.w};
#pragma unroll
    for (int i = 0; i < 4; ++i) {
      const unsigned short hb = f2b(c[i]);
      Whi[base + i] = hb;
      Wlo[base + i] = f2b(c[i] - b2f(hb));
    }
    return;
  }

  const int w = tid >> 6, l = tid & 63;
  const int lg = l >> 4, lr = l & 15;
  const int t0 = blockIdx.x * 32 + (w & 1) * 16;

  if (by < 4) {
    // ---- Q projection: Qs[b][h][m][d] = bf16(0.25 * (Xq @ Wq^T)) ----
    const int n0 = by * 64 + (w >> 1) * 32;
    f32x4 acc0 = {0.f, 0.f, 0.f, 0.f}, acc1 = {0.f, 0.f, 0.f, 0.f};
#pragma unroll
    for (int kc = 0; kc < EE; kc += 32) {
      const int k = kc + lg * 8;
      bf16x8 a  = cvt8(Xq + (size_t)(t0 + lr) * EE + k);
      bf16x8 b0 = cvt8(Wq + (size_t)(n0 + lr) * EE + k);
      bf16x8 b1 = cvt8(Wq + (size_t)(n0 + 16 + lr) * EE + k);
      acc0 = __builtin_amdgcn_mfma_f32_16x16x32_bf16(a, b0, acc0, 0, 0, 0);
      acc1 = __builtin_amdgcn_mfma_f32_16x16x32_bf16(a, b1, acc1, 0, 0, 0);
    }
#pragma unroll
    for (int r = 0; r < 4; ++r) {
      const int t = t0 + 4 * lg + r, b = t >> 9, m = t & 511;
      const int j0 = n0 + lr, j1 = j0 + 16;
      Qs[((size_t)(b * HH + (j0 >> 4)) * MM + m) * DD + (j0 & 15)] = f2b(acc0[r] * 0.25f);
      Qs[((size_t)(b * HH + (j1 >> 4)) * MM + m) * DD + (j1 & 15)] = f2b(acc1[r] * 0.25f);
    }
  } else {
    // ---- KV projection: rows j<256 -> Ks[b][h][n][d]; j>=256 -> Vt[b][h][d][n] ----
    const int n0 = (by - 4) * 64 + (w >> 1) * 32;
    f32x4 acc0 = {0.f, 0.f, 0.f, 0.f}, acc1 = {0.f, 0.f, 0.f, 0.f};
#pragma unroll
    for (int kc = 0; kc < EE; kc += 32) {
      const int k = kc + lg * 8;
      bf16x8 a  = cvt8(Xkv + (size_t)(t0 + lr) * EE + k);
      bf16x8 b0 = cvt8(Wkv + (size_t)(n0 + lr) * EE + k);
      bf16x8 b1 = cvt8(Wkv + (size_t)(n0 + 16 + lr) * EE + k);
      acc0 = __builtin_amdgcn_mfma_f32_16x16x32_bf16(a, b0, acc0, 0, 0, 0);
      acc1 = __builtin_amdgcn_mfma_f32_16x16x32_bf16(a, b1, acc1, 0, 0, 0);
    }
#pragma unroll
    for (int r = 0; r < 4; ++r) {
      const int t = t0 + 4 * lg + r, b = t >> 9, n = t & 511;
#pragma unroll
      for (int fi = 0; fi < 2; ++fi) {
        const int j = n0 + lr + fi * 16;
        const float v = fi ? acc1[r] : acc0[r];
        if (j < 256) {
          Ks[((size_t)(b * HH + (j >> 4)) * NN + n) * DD + (j & 15)] = f2b(v);
        } else {
          const int jj = j - 256;
          Vt[((size_t)(b * HH + (jj >> 4)) * DD + (jj & 15)) * NN + n] = f2b(v);
        }
      }
    }
  }
}

// ---------------------------------------------------------------------------
// Fused attention: scores(MFMA) -> MLP mix (VALU on C-frags) -> no-max softmax
// -> PV (MFMA) -> hi/lo bf16 output. One block = (b, head, 32-row m-tile).
// 4 waves, each owns 128 n-columns.
// ---------------------------------------------------------------------------
__global__ __launch_bounds__(256) void attn_kernel(
    const unsigned short* __restrict__ Qs, const unsigned short* __restrict__ Ks,
    const unsigned short* __restrict__ Vt, const float* __restrict__ dmat,
    const float* __restrict__ W1, const float* __restrict__ b1v,
    const float* __restrict__ W2,
    unsigned short* __restrict__ Ahi, unsigned short* __restrict__ Alo) {
  __shared__ unsigned short P[32][520];   // exp'd (unnormalized) probs, bf16
  __shared__ float red[4][32];            // per-wave row sums
  __shared__ float pvred[4][2][16][16];   // PV partials per wave

  const int tid = threadIdx.x, w = tid >> 6, l = tid & 63;
  const int lg = l >> 4, lr = l & 15;
  const int bid = blockIdx.x;
  const int mt = bid & 15, hh = (bid >> 4) & 15, b = bid >> 8;
  const int m0 = mt * 32;
  const int n0 = w * 128;

  const unsigned short* Qbase = Qs + ((size_t)(b * HH + hh) * MM + m0) * DD;
  const unsigned short* Kbase = Ks + (size_t)(b * HH + hh) * NN * DD;
  const unsigned short* Vbase = Vt + (size_t)(b * HH + hh) * DD * NN;
  const float* dbase = dmat + (size_t)b * MM * NN;

  // Q A-fragments, zero-padded in K upper half (D=16 < K=32)
  bf16x8 qa[2];
#pragma unroll
  for (int mb = 0; mb < 2; ++mb) {
    qa[mb] = bzero8();
    if (lg < 2) qa[mb] = *(const bf16x8*)(Qbase + (mb * 16 + lr) * DD + lg * 8);
  }

  f32x4 zf = {0.f, 0.f, 0.f, 0.f};
  f32x4 c[2][8];
#pragma unroll
  for (int mb = 0; mb < 2; ++mb)
#pragma unroll
    for (int nb = 0; nb < 8; ++nb) c[mb][nb] = zf;

#pragma unroll
  for (int nb = 0; nb < 8; ++nb) {
    bf16x8 kb = bzero8();
    if (lg < 2)
      kb = *(const bf16x8*)(Kbase + (size_t)(n0 + nb * 16 + lr) * DD + lg * 8);
    c[0][nb] = __builtin_amdgcn_mfma_f32_16x16x32_bf16(qa[0], kb, c[0][nb], 0, 0, 0);
    c[1][nb] = __builtin_amdgcn_mfma_f32_16x16x32_bf16(qa[1], kb, c[1][nb], 0, 0, 0);
  }

  // MLP coefficients, forced to SGPRs (block-uniform).
  // relu(x)=(x+|x|)/2; fold 0.5*W2 and 1/ln2 (for raw v_exp) into wk:
  //   mixed/ln2 = Ac*s + Cc*d + sum_k wk*|ak*s + ck*d + bk|  (+row-const, dropped)
  float ak[16], ck[16], bk[16], wk[16];
  float Ac = 0.f, Cc = 0.f;
  const float hiln2 = 0.5f * 1.4426950408889634f;
#pragma unroll
  for (int k = 0; k < 16; ++k) {
    ak[k] = sload(W1 + hh * 32 + k);
    ck[k] = sload(W1 + hh * 32 + 16 + k);
    bk[k] = sload(b1v + hh * 16 + k);
    wk[k] = hiln2 * sload(W2 + hh * 16 + k);
    Ac += wk[k] * ak[k];
    Cc += wk[k] * ck[k];
  }

  // MLP + exp (no max subtraction: |mixed| analytically bounded ~14)
  float psum[2][4] = {};
#pragma unroll
  for (int mb = 0; mb < 2; ++mb) {
    const int mrow = m0 + mb * 16 + 4 * lg;
#pragma unroll
    for (int nb = 0; nb < 8; ++nb) {
      const int ncol = n0 + nb * 16 + lr;
      const float* dp = dbase + (size_t)mrow * NN + ncol;
      float dv[4];
#pragma unroll
      for (int r = 0; r < 4; ++r) dv[r] = dp[(size_t)r * NN];
#pragma unroll
      for (int r = 0; r < 4; ++r) {
        const float s = c[mb][nb][r];
        const float d = dv[r];
        float acc = fmaf(Ac, s, Cc * d);
#pragma unroll
        for (int k = 0; k < 16; ++k) {
          const float t = fmaf(ak[k], s, fmaf(ck[k], d, bk[k]));
          acc = fmaf(wk[k], fabsf(t), acc);
        }
        const float e = fexp2(acc);
        psum[mb][r] += e;
        P[mb * 16 + 4 * lg + r][n0 + nb * 16 + lr] = f2b(e);
      }
    }
  }

  // row-sum: shfl within 16-lane group, stash per-wave partials
#pragma unroll
  for (int mb = 0; mb < 2; ++mb)
#pragma unroll
    for (int r = 0; r < 4; ++r) {
#pragma unroll
      for (int off = 8; off > 0; off >>= 1)
        psum[mb][r] += __shfl_xor(psum[mb][r], off, 16);
      if (lr == 0) red[w][mb * 16 + 4 * lg + r] = psum[mb][r];
    }

  // PV over this wave's own n-range (P rows self-written: intra-wave lgkmcnt dep)
  f32x4 pv[2];
  pv[0] = zf; pv[1] = zf;
#pragma unroll
  for (int kb = 0; kb < 4; ++kb) {
    const bf16x8 vb = *(const bf16x8*)(Vbase + (size_t)lr * NN + (n0 + kb * 32 + lg * 8));
#pragma unroll
    for (int mb = 0; mb < 2; ++mb) {
      const bf16x8 pa = *(const bf16x8*)(&P[mb * 16 + lr][n0 + kb * 32 + lg * 8]);
      pv[mb] = __builtin_amdgcn_mfma_f32_16x16x32_bf16(pa, vb, pv[mb], 0, 0, 0);
    }
  }
#pragma unroll
  for (int mb = 0; mb < 2; ++mb)
#pragma unroll
    for (int r = 0; r < 4; ++r) pvred[w][mb][4 * lg + r][lr] = pv[mb][r];
  __syncthreads();

  // epilogue: combine wave partials, normalize, emit hi/lo bf16
  for (int i = tid; i < 512; i += 256) {
    const int mr = i >> 4, dd = i & 15;
    const float s = pvred[0][mr >> 4][mr & 15][dd] + pvred[1][mr >> 4][mr & 15][dd] +
                    pvred[2][mr >> 4][mr & 15][dd] + pvred[3][mr >> 4][mr & 15][dd];
    const float rs = red[0][mr] + red[1][mr] + red[2][mr] + red[3][mr];
    const float val = s / rs;
    const unsigned short hb = f2b(val);
    const size_t o = ((size_t)(b * MM) + m0 + mr) * EE + hh * DD + dd;
    Ahi[o] = hb;
    Alo[o] = f2b(val - b2f(hb));
  }
}

// ---------------------------------------------------------------------------
// Final projection via bf16 MFMA with hi/lo split (~fp32 accuracy):
// out = Ahi@Whi^T + Alo@Whi^T + Ahi@Wlo^T
// ---------------------------------------------------------------------------
__global__ __launch_bounds__(256) void out_gemm_kernel(
    const unsigned short* __restrict__ Ahi, const unsigned short* __restrict__ Alo,
    const unsigned short* __restrict__ Whi, const unsigned short* __restrict__ Wlo,
    float* __restrict__ out) {
  const int tid = threadIdx.x, w = tid >> 6, l = tid & 63;
  const int lg = l >> 4, lr = l & 15;
  const int t0 = blockIdx.x * 32 + (w & 1) * 16;
  const int n0 = blockIdx.y * 64 + (w >> 1) * 32;
  f32x4 acc0 = {0.f, 0.f, 0.f, 0.f}, acc1 = {0.f, 0.f, 0.f, 0.f};
#pragma unroll
  for (int kc = 0; kc < EE; kc += 32) {
    const int k = kc + lg * 8;
    const bf16x8 ah = *(const bf16x8*)(Ahi + (size_t)(t0 + lr) * EE + k);
    const bf16x8 al = *(const bf16x8*)(Alo + (size_t)(t0 + lr) * EE + k);
    const bf16x8 bh0 = *(const bf16x8*)(Whi + (size_t)(n0 + lr) * EE + k);
    const bf16x8 bh1 = *(const bf16x8*)(Whi + (size_t)(n0 + 16 + lr) * EE + k);
    const bf16x8 bl0 = *(const bf16x8*)(Wlo + (size_t)(n0 + lr) * EE + k);
    const bf16x8 bl1 = *(const bf16x8*)(Wlo + (size_t)(n0 + 16 + lr) * EE + k);
    acc0 = __builtin_amdgcn_mfma_f32_16x16x32_bf16(ah, bh0, acc0, 0, 0, 0);
    acc0 = __builtin_amdgcn_mfma_f32_16x16x32_bf16(al, bh0, acc0, 0, 0, 0);
    acc0 = __builtin_amdgcn_mfma_f32_16x16x32_bf16(ah, bl0, acc0, 0, 0, 0);
    acc1 = __builtin_amdgcn_mfma_f32_16x16x32_bf16(ah, bh1, acc1, 0, 0, 0);
    acc1 = __builtin_amdgcn_mfma_f32_16x16x32_bf16(al, bh1, acc1, 0, 0, 0);
    acc1 = __builtin_amdgcn_mfma_f32_16x16x32_bf16(ah, bl1, acc1, 0, 0, 0);
  }
#pragma unroll
  for (int r = 0; r < 4; ++r) {
    const int row = t0 + 4 * lg + r;
    out[(size_t)row * EE + n0 + lr] = acc0[r];
    out[(size_t)row * EE + n0 + 16 + lr] = acc1[r];
  }
}

// ---------------------------------------------------------------------------
extern "C" void kernel_launch(void* const* d_in, const int* in_sizes, int n_in,
                              void* d_out, int out_size, void* d_ws, size_t ws_size,
                              hipStream_t stream) {
  const float* q_input  = (const float*)d_in[0];
  const float* kv_input = (const float*)d_in[1];
  const float* dmat     = (const float*)d_in[2];
  const float* Wq       = (const float*)d_in[3];
  const float* Wkv      = (const float*)d_in[4];
  const float* W1       = (const float*)d_in[5];
  const float* b1       = (const float*)d_in[6];
  const float* W2       = (const float*)d_in[7];
  // d_in[8] = mix_b2: per-row constant inside softmax -> no effect, unused
  const float* Wout     = (const float*)d_in[9];
  float* out = (float*)d_out;

  char* ws = (char*)d_ws;
  unsigned short* Qs  = (unsigned short*)(ws);                        // 1 MB bf16 [B][H][M][D]
  unsigned short* Ks  = (unsigned short*)(ws + (1u << 20));           // 1 MB bf16 [B][H][N][D]
  unsigned short* Vt  = (unsigned short*)(ws + (2u << 20));           // 1 MB bf16 [B][H][D][N]
  unsigned short* Ahi = (unsigned short*)(ws + (3u << 20));           // 1 MB bf16 [B*M][E]
  unsigned short* Alo = (unsigned short*)(ws + (4u << 20));           // 1 MB bf16 [B*M][E]
  unsigned short* Whi = (unsigned short*)(ws + (5u << 20));           // 128 KB
  unsigned short* Wlo = (unsigned short*)(ws + (5u << 20) + (1u << 17)); // 128 KB

  proj_all_kernel<<<dim3(64, 13), 256, 0, stream>>>(q_input, kv_input, Wq, Wkv, Wout,
                                                    Qs, Ks, Vt, Whi, Wlo);
  attn_kernel<<<dim3(1024), 256, 0, stream>>>(Qs, Ks, Vt, dmat, W1, b1, W2, Ahi, Alo);
  out_gemm_kernel<<<dim3(64, 4), 256, 0, stream>>>(Ahi, Alo, Whi, Wlo, out);
}